// Round 6
// baseline (153.545 us; speedup 1.0000x reference)
//
#include <hip/hip_runtime.h>

// YOLO-style loss: y_pred (1024,28,28,30) f32, y_true (1024,28,28,5) f32 -> scalar f32.
// ~113 MB read; L3 absorbs ~half (FETCH_SIZE 56 MB) -> kernel floor ~10-15us.
// Harness fixed overhead (input restore + 385MB 0xAA fills) ~= 112us of dur_us.
// R1 55us: strided loads, VMEM-transaction-bound. R2 65us: +same-address atomics.
// R3 45us: partials+inline stream. R4 40us: global_load_lds. R5 38us: barrier-free
// wave-private staging. Lesson: every version pays one full exposed global-load
// latency per wave (load->LDS->compute serial chain, one tile per wave).
// R6: persistent waves, ~3 tiles each, software-pipelined: tile t+stride's loads
// fly while tile t computes from LDS. No barriers; acc carried; reduce once.

#define S_GRID 28
#define N_CELLS (1024 * S_GRID * S_GRID)     // 802816
#define CPW 64                               // cells per tile (= lanes)
#define NT (N_CELLS / CPW)                   // 12544 tiles
#define WPB 4
#define BLOCK (WPB * 64)                     // 256
#define NBLOCKS 1024
#define TOTW (NBLOCKS * WPB)                 // 4096 waves; 12544/4096 = 3.0625 tiles/wave

__device__ __forceinline__ float iou_calc(float bx, float by, float bw, float bh,
                                          float tx, float ty, float tw, float th,
                                          float gi, float gj) {
    float acx = (gj + bx) * 8.0f;
    float acy = (gi + by) * 8.0f;
    float aw  = bw * 224.0f;
    float ah  = bh * 224.0f;
    float ax1 = acx - aw * 0.5f, ax2 = acx + aw * 0.5f;
    float ay1 = acy - ah * 0.5f, ay2 = acy + ah * 0.5f;
    float bcx = (gj + tx) * 8.0f;
    float bcy = (gi + ty) * 8.0f;
    float btw = tw * 224.0f;
    float bth = th * 224.0f;
    float bx1 = bcx - btw * 0.5f, bx2 = bcx + btw * 0.5f;
    float by1 = bcy - bth * 0.5f, by2 = bcy + bth * 0.5f;

    float iw = fmaxf(fminf(ax2, bx2) - fmaxf(ax1, bx1), 0.0f);
    float ih = fmaxf(fminf(ay2, by2) - fmaxf(ay1, by1), 0.0f);
    float inter = iw * ih;
    float area_a = fmaxf(ax2 - ax1, 0.0f) * fmaxf(ay2 - ay1, 0.0f);
    float area_b = fmaxf(bx2 - bx1, 0.0f) * fmaxf(by2 - by1, 0.0f);
    return inter / (area_a + area_b - inter + 1e-12f);
}

__global__ __launch_bounds__(BLOCK) void yolo_loss_kernel(const float2* __restrict__ yp2,
                                                          const float* __restrict__ yt,
                                                          float* __restrict__ partials) {
    // wave-private pred slab, raw layout: 64 cells x 30 floats = 7680 B / wave
    __shared__ float sp[WPB][CPW * 30];      // 30720 B -> 4 blocks/CU

    int tid  = threadIdx.x;
    int lane = tid & 63;
    int wave = tid >> 6;
    int wid  = blockIdx.x * WPB + wave;      // 0..4095

    float acc = 0.0f;

    // ---- prologue: issue loads for first tile ----
    float2 v[15];
    float t5[5];
    {
        const float2* pb = yp2 + (size_t)wid * (CPW * 30 / 2);
#pragma unroll
        for (int k = 0; k < 15; ++k) v[k] = pb[k * 64 + lane];
        const float* tt = yt + ((size_t)wid * CPW + lane) * 5;
#pragma unroll
        for (int k = 0; k < 5; ++k) t5[k] = tt[k];
    }

    float2* spw2 = (float2*)sp[wave];

    for (int t = wid; t < NT; t += TOTW) {
        // ---- stage current tile regs -> wave-private LDS (conflict-free) ----
#pragma unroll
        for (int k = 0; k < 15; ++k) spw2[k * 64 + lane] = v[k];
        float tc = t5[0], tx = t5[1], ty = t5[2], tw = t5[3], th = t5[4];

        // ---- prefetch next tile (loads fly while we compute below) ----
        int tn = t + TOTW;
        if (tn < NT) {
            const float2* pbn = yp2 + (size_t)tn * (CPW * 30 / 2);
#pragma unroll
            for (int k = 0; k < 15; ++k) v[k] = pbn[k * 64 + lane];
            const float* ttn = yt + ((size_t)tn * CPW + lane) * 5;
#pragma unroll
            for (int k = 0; k < 5; ++k) t5[k] = ttn[k];
        }

        // ---- per-cell compute from LDS (stride 30: 4-way aliasing, ~free) ----
        int cell = t * CPW + lane;
        int ij = cell % (S_GRID * S_GRID);
        float gi = (float)(ij / S_GRID);
        float gj = (float)(ij % S_GRID);

        float pr[30];
        const float* p = sp[wave] + lane * 30;
#pragma unroll
        for (int k = 0; k < 30; ++k) pr[k] = p[k];

        float iou0 = iou_calc(pr[0], pr[1], pr[2], pr[3], tx, ty, tw, th, gi, gj);
        float iou1 = iou_calc(pr[5], pr[6], pr[7], pr[8], tx, ty, tw, th, gi, gj);
        bool choose1 = !(iou0 > iou1);

        float conf_pred = choose1 ? pr[9] : pr[4];
        float conf_true = choose1 ? iou1 : iou0;
        float xp = choose1 ? pr[5] : pr[0];
        float yp = choose1 ? pr[6] : pr[1];

        float dcf = conf_pred - conf_true;
        float d0 = xp - tx, d1 = yp - ty;

        int cls = (int)tc - 1;   // -1 => one-hot all zeros
        float lcls = 0.0f;
#pragma unroll
        for (int k = 0; k < 20; ++k) {
            float oh = (k == cls) ? 1.0f : 0.0f;
            float d = pr[10 + k] - oh;
            lcls += d * d;
        }

        float obj_loss   = dcf * dcf + 5.0f * (d0 * d0 + d1 * d1) + lcls;
        float noobj_loss = 0.5f * (pr[4] * pr[4] + pr[9] * pr[9]);
        acc += (tc != 0.0f) ? obj_loss : noobj_loss;
    }

    // ---- one wave-local reduction at the end; one partial per wave ----
#pragma unroll
    for (int off = 32; off > 0; off >>= 1) {
        acc += __shfl_down(acc, off, 64);
    }
    if (lane == 0) partials[wid] = acc;
}

__global__ __launch_bounds__(256) void reduce_kernel(const float* __restrict__ partials,
                                                     float* __restrict__ out) {
    int tid = threadIdx.x;
    float s = 0.0f;
#pragma unroll
    for (int k = 0; k < 16; ++k) {           // 16 * 256 = 4096 exact
        s += partials[k * 256 + tid];
    }
#pragma unroll
    for (int off = 32; off > 0; off >>= 1) {
        s += __shfl_down(s, off, 64);
    }
    __shared__ float wsum[4];
    int lane = tid & 63;
    int wid  = tid >> 6;
    if (lane == 0) wsum[wid] = s;
    __syncthreads();
    if (tid == 0) {
        out[0] = (wsum[0] + wsum[1] + wsum[2] + wsum[3]) * (1.0f / 1024.0f);
    }
}

extern "C" void kernel_launch(void* const* d_in, const int* in_sizes, int n_in,
                              void* d_out, int out_size, void* d_ws, size_t ws_size,
                              hipStream_t stream) {
    const float2* y_pred = (const float2*)d_in[0];
    const float*  y_true = (const float*)d_in[1];
    float* out = (float*)d_out;
    float* partials = (float*)d_ws;   // 4096 floats, fully overwritten each call

    yolo_loss_kernel<<<NBLOCKS, BLOCK, 0, stream>>>(y_pred, y_true, partials);
    reduce_kernel<<<1, 256, 0, stream>>>(partials, out);
}

// Round 7
// 151.147 us; speedup vs baseline: 1.0159x; 1.0159x over previous
//
#include <hip/hip_runtime.h>

// YOLO-style loss: y_pred (1024,28,28,30) f32, y_true (1024,28,28,5) f32 -> scalar f32.
// ~113 MB read; L3 absorbs ~half -> BW floor ~10-15us; harness fixed overhead ~110us.
// R1 55us strided loads (VMEM line-bound, model validated: ~1 cyc/line-touch/instr).
// R2 65us atomics. R3 45us. R4 40us global_load_lds. R5 38us barrier-free wave-private.
// R6 38us pipelined (neutral -> latency not the limiter).
// R7 theory: plateau = per-tile serial cycles at low DPM clock; cut cycles:
//   float2 LDS readback (30 ds_read_b32 -> ~8 b64-class), class loss via
//   sumsq - 2*p[cls] + 1 (one dynamic LDS read replaces 20-way cndmask loop),
//   y_true staged wave-private (kills 5 scattered-line loads/tile).

#define S_GRID 28
#define N_CELLS (1024 * S_GRID * S_GRID)     // 802816
#define CPW 64                               // cells per tile (= lanes)
#define NT (N_CELLS / CPW)                   // 12544 tiles
#define WPB 4
#define BLOCK (WPB * 64)                     // 256
#define NBLOCKS (NT / WPB)                   // 3136

__device__ __forceinline__ float iou_calc(float bx, float by, float bw, float bh,
                                          float tx, float ty, float tw, float th,
                                          float gi, float gj) {
    float acx = (gj + bx) * 8.0f;
    float acy = (gi + by) * 8.0f;
    float aw  = bw * 224.0f;
    float ah  = bh * 224.0f;
    float ax1 = acx - aw * 0.5f, ax2 = acx + aw * 0.5f;
    float ay1 = acy - ah * 0.5f, ay2 = acy + ah * 0.5f;
    float bcx = (gj + tx) * 8.0f;
    float bcy = (gi + ty) * 8.0f;
    float btw = tw * 224.0f;
    float bth = th * 224.0f;
    float bx1 = bcx - btw * 0.5f, bx2 = bcx + btw * 0.5f;
    float by1 = bcy - bth * 0.5f, by2 = bcy + bth * 0.5f;

    float iw = fmaxf(fminf(ax2, bx2) - fmaxf(ax1, bx1), 0.0f);
    float ih = fmaxf(fminf(ay2, by2) - fmaxf(ay1, by1), 0.0f);
    float inter = iw * ih;
    float area_a = fmaxf(ax2 - ax1, 0.0f) * fmaxf(ay2 - ay1, 0.0f);
    float area_b = fmaxf(bx2 - bx1, 0.0f) * fmaxf(by2 - by1, 0.0f);
    return inter / (area_a + area_b - inter + 1e-12f);
}

__global__ __launch_bounds__(BLOCK) void yolo_loss_kernel(const float2* __restrict__ yp2,
                                                          const float2* __restrict__ yt2,
                                                          float* __restrict__ partials) {
    __shared__ float sp[WPB][CPW * 30];      // 7680 B / wave, raw layout
    __shared__ float st[WPB][CPW * 5];       // 1280 B / wave, raw layout

    int tid  = threadIdx.x;
    int lane = tid & 63;
    int wave = tid >> 6;
    int wid  = blockIdx.x * WPB + wave;      // tile id, 0..12543

    // ---- coalesced loads: y_pred 960 float2, y_true 160 float2 per tile ----
    const float2* pb = yp2 + (size_t)wid * 960;
    float2 v[15];
#pragma unroll
    for (int k = 0; k < 15; ++k) v[k] = pb[k * 64 + lane];

    const float2* tb = yt2 + (size_t)wid * 160;
    float2 u0 = tb[lane];
    float2 u1 = tb[64 + lane];
    float2 u2 = (lane < 32) ? tb[128 + lane] : make_float2(0.0f, 0.0f);

    // ---- wave-private LDS staging, raw layout (lane-contiguous, conflict-free) ----
    float2* spw = (float2*)sp[wave];
#pragma unroll
    for (int k = 0; k < 15; ++k) spw[k * 64 + lane] = v[k];
    float2* stw = (float2*)st[wave];
    stw[lane] = u0;
    stw[64 + lane] = u1;
    if (lane < 32) stw[128 + lane] = u2;
    // same-wave LDS ordering: compiler inserts lgkmcnt waits; no barrier needed.

    // ---- read own cell: 15 float2 (b64-class reads) + 5 y_true (stride 5, conflict-free) ----
    float pr[30];
    const float2* pc = (const float2*)(sp[wave] + lane * 30);
#pragma unroll
    for (int k = 0; k < 15; ++k) {
        float2 w = pc[k];
        pr[2 * k] = w.x;
        pr[2 * k + 1] = w.y;
    }
    const float* tcell = st[wave] + lane * 5;
    float tc = tcell[0], tx = tcell[1], ty = tcell[2], tw = tcell[3], th = tcell[4];

    // ---- per-cell loss ----
    int cell = wid * CPW + lane;
    int ij = cell % (S_GRID * S_GRID);
    float gi = (float)(ij / S_GRID);
    float gj = (float)(ij % S_GRID);

    float iou0 = iou_calc(pr[0], pr[1], pr[2], pr[3], tx, ty, tw, th, gi, gj);
    float iou1 = iou_calc(pr[5], pr[6], pr[7], pr[8], tx, ty, tw, th, gi, gj);
    bool choose1 = !(iou0 > iou1);

    float conf_pred = choose1 ? pr[9] : pr[4];
    float conf_true = choose1 ? iou1 : iou0;
    float xp = choose1 ? pr[5] : pr[0];
    float yp = choose1 ? pr[6] : pr[1];

    float dcf = conf_pred - conf_true;
    float d0 = xp - tx, d1 = yp - ty;

    // class loss: sum((p - onehot)^2) = sumsq - 2*p[cls] + 1   (cls valid <=> obj)
    float sumsq = 0.0f;
#pragma unroll
    for (int k = 10; k < 30; ++k) sumsq = fmaf(pr[k], pr[k], sumsq);
    int cls = (int)tc - 1;                    // tc in {0..20}; obj <=> cls >= 0
    int cidx = cls < 0 ? 0 : cls;
    float pcls = sp[wave][lane * 30 + 10 + cidx];   // one dynamic LDS read
    float lcls = (cls >= 0) ? (sumsq - 2.0f * pcls + 1.0f) : sumsq;

    float obj_loss   = dcf * dcf + 5.0f * (d0 * d0 + d1 * d1) + lcls;
    float noobj_loss = 0.5f * (pr[4] * pr[4] + pr[9] * pr[9]);
    float val = (tc != 0.0f) ? obj_loss : noobj_loss;

    // ---- wave-local reduce; one partial per wave; NO barrier ----
#pragma unroll
    for (int off = 32; off > 0; off >>= 1) {
        val += __shfl_down(val, off, 64);
    }
    if (lane == 0) partials[wid] = val;
}

__global__ __launch_bounds__(256) void reduce_kernel(const float* __restrict__ partials,
                                                     float* __restrict__ out) {
    int tid = threadIdx.x;
    float s = 0.0f;
#pragma unroll
    for (int k = 0; k < 49; ++k) {           // 49 * 256 = 12544 exact
        s += partials[k * 256 + tid];
    }
#pragma unroll
    for (int off = 32; off > 0; off >>= 1) {
        s += __shfl_down(s, off, 64);
    }
    __shared__ float wsum[4];
    int lane = tid & 63;
    int wid  = tid >> 6;
    if (lane == 0) wsum[wid] = s;
    __syncthreads();
    if (tid == 0) {
        out[0] = (wsum[0] + wsum[1] + wsum[2] + wsum[3]) * (1.0f / 1024.0f);
    }
}

extern "C" void kernel_launch(void* const* d_in, const int* in_sizes, int n_in,
                              void* d_out, int out_size, void* d_ws, size_t ws_size,
                              hipStream_t stream) {
    const float2* y_pred = (const float2*)d_in[0];
    const float2* y_true = (const float2*)d_in[1];
    float* out = (float*)d_out;
    float* partials = (float*)d_ws;   // 12544 floats, fully overwritten each call

    yolo_loss_kernel<<<NBLOCKS, BLOCK, 0, stream>>>(y_pred, y_true, partials);
    reduce_kernel<<<1, 256, 0, stream>>>(partials, out);
}